// Round 5
// baseline (4384.969 us; speedup 1.0000x reference)
//
#include <hip/hip_runtime.h>
#include <math.h>

// Problem constants: T=512, B=64, I=256, H=1024, O=256
// d_out layout: outputs [512*64][256] fp32, then hidden_states [512*64][1024] fp32.

typedef __attribute__((ext_vector_type(8))) short s16x8;
typedef __attribute__((ext_vector_type(4))) short s16x4;
typedef __attribute__((ext_vector_type(4))) float f32x4;

__device__ __forceinline__ short f2bf(float f) {
  union { float f; unsigned u; } v; v.f = f;
  unsigned r = v.u + 0x7FFFu + ((v.u >> 16) & 1u);  // RNE
  return (short)(r >> 16);
}

__device__ __forceinline__ f32x4 mfma16(s16x8 a, s16x8 b, f32x4 c) {
  return __builtin_amdgcn_mfma_f32_16x16x32_bf16(a, b, c, 0, 0, 0);
}

// tanh via v_exp_f32: t = 1 - 2/(e^{2x}+1). Monotone-safe at +-inf, no NaN.
__device__ __forceinline__ float fast_tanh(float x) {
  float e = __expf(2.0f * x);
  return 1.0f - 2.0f * __builtin_amdgcn_rcpf(e + 1.0f);
}

// ---------------- converters / init ----------------

__global__ void cvt_bf16x4(const float* __restrict__ in, short* __restrict__ out, int n4) {
  int i = blockIdx.x * 256 + threadIdx.x;
  if (i < n4) {
    const float4 v = ((const float4*)in)[i];
    s16x4 o = { f2bf(v.x), f2bf(v.y), f2bf(v.z), f2bf(v.w) };
    ((s16x4*)out)[i] = o;
  }
}

// staging slot 0 = h_{-1} = broadcast h0 over 64 rows.
__global__ void init_staging(const float* __restrict__ h0, short* __restrict__ staging) {
  int i = blockIdx.x * 256 + threadIdx.x;  // 64*1024 = 65536
  if (i < 65536) staging[i] = f2bf(h0[i & 1023]);
}

// ---------------- generic NT GEMM: out[M][N] = A[M][K](bf16) * B[N][K](bf16)^T + bias ----------------

template <int K>
__global__ __launch_bounds__(256) void gemm_nt_bias(
    const short* __restrict__ A, const short* __restrict__ B,
    const float* __restrict__ bias, float* __restrict__ out, int N) {
  const int tid = threadIdx.x;
  const int lane = tid & 63, wv = tid >> 6;
  const int m0 = blockIdx.x * 64 + (wv & 1) * 32;
  const int n0 = blockIdx.y * 64 + (wv >> 1) * 32;
  const int lm = lane & 15, q = lane >> 4;

  const short* a0p = A + (m0 + lm) * K + q * 8;
  const short* a1p = a0p + 16 * K;
  const short* b0p = B + (n0 + lm) * K + q * 8;
  const short* b1p = b0p + 16 * K;

  f32x4 c00 = {0.f,0.f,0.f,0.f}, c01 = {0.f,0.f,0.f,0.f};
  f32x4 c10 = {0.f,0.f,0.f,0.f}, c11 = {0.f,0.f,0.f,0.f};

#pragma unroll
  for (int kk = 0; kk < K; kk += 32) {
    s16x8 a0 = *(const s16x8*)(a0p + kk);
    s16x8 a1 = *(const s16x8*)(a1p + kk);
    s16x8 b0 = *(const s16x8*)(b0p + kk);
    s16x8 b1 = *(const s16x8*)(b1p + kk);
    c00 = mfma16(a0, b0, c00);
    c01 = mfma16(a0, b1, c01);
    c10 = mfma16(a1, b0, c10);
    c11 = mfma16(a1, b1, c11);
  }

  const int col0 = n0 + lm;
  const float bi0 = bias[col0], bi1 = bias[col0 + 16];
#pragma unroll
  for (int r = 0; r < 4; ++r) {
    int row = m0 + q * 4 + r;
    out[row * N + col0]        = c00[r] + bi0;
    out[row * N + col0 + 16]   = c01[r] + bi1;
    out[(row + 16) * N + col0]      = c10[r] + bi0;
    out[(row + 16) * N + col0 + 16] = c11[r] + bi1;
  }
}

// ---------------- recurrent kernel ----------------
// 256 WGs of 64 threads (1 wave). group g = bid&7 owns batch rows [8g,8g+8);
// col-wg c = bid>>3 owns hidden cols [32c,32c+32). wR slice lives in 256 regs.
//
// R4 lesson: 64 relaxed-atomic 8B h-loads/lane serialize (~16k cy/step —
// LLVM won't pipeline monotonic atomics). Fix: T-deep staging ring, one slot
// per step (slot t = h_{t-1}), so every address is written once / read once
// per launch -> consumer L1/L2 can never hold a stale copy -> plain b128
// loads, fully pipelined by vmcnt. Producers still store via sc0 sc1
// (write-through to the L3 coherence point), ack with s_waitcnt vmcnt(0),
// then set per-(t,g,c) flag. No fences anywhere (R1: fence = wbl2/inv storm).
// The ring doubles as hidden_states in bf16 (time-shifted): phase C reads
// staging+65536 directly; hs_bf eliminated.

__global__ __launch_bounds__(64, 1) void rnn_recur(
    const float* __restrict__ wR,     // [1024][1024] fp32, k-major
    float* __restrict__ hid,          // [512*64][1024] fp32: xp on entry, h on exit
    short* __restrict__ staging,      // [513][64][1024] bf16: slot t = h_{t-1}
    int* __restrict__ flags)          // [512][8][32]
{
  __shared__ short lh[256];           // 8 rows x 32 cols bf16 repack buffer

  const int lane = threadIdx.x;
  const int g = blockIdx.x & 7;
  const int c = blockIdx.x >> 3;
  const int m = lane & 15, q = lane >> 4;
  const int rowbase = g * 8;
  const int colbase = c * 32;

  // --- one-time: pack wR[:, colbase..colbase+32) into B-fragments in registers ---
  s16x8 bf[32][2];
#pragma unroll
  for (int cc = 0; cc < 32; ++cc) {
#pragma unroll
    for (int tn = 0; tn < 2; ++tn) {
      const int kb = cc * 32 + q * 8;
      const int n = colbase + tn * 16 + m;
      s16x8 v;
#pragma unroll
      for (int j = 0; j < 8; ++j) v[j] = f2bf(wR[(kb + j) * 1024 + n]);
      bf[cc][tn] = v;
    }
  }

  const int arow = rowbase + (m & 7);  // lanes m>=8 duplicate rows 0..7
  const int gr = rowbase + q * 4;      // epilogue rows (valid when q<2)
  const int lr = q * 4;                // local row base in lh
  // packed-store mapping: lane i handles 8 bytes = 4 cols: row i>>3, col (i&7)*4
  const int prow = lane >> 3, pcol = (lane & 7) * 4;

#pragma unroll 1
  for (int t = 0; t < 512; ++t) {
    const int tb = t * 64;

    // prefetch xp (independent of the flag) to hide latency behind the poll
    float xp0[4] = {0.f,0.f,0.f,0.f}, xp1[4] = {0.f,0.f,0.f,0.f};
    if (q < 2) {
#pragma unroll
      for (int r = 0; r < 4; ++r) {
        int ro = (tb + gr + r) * 1024;
        xp0[r] = hid[ro + colbase + m];
        xp1[r] = hid[ro + colbase + 16 + m];
      }
    }

    if (t > 0) {
      const int* fl = flags + (t - 1) * 256 + g * 32;
      for (;;) {
        int v = 1;
        if (lane < 32)
          v = __hip_atomic_load(fl + lane, __ATOMIC_RELAXED, __HIP_MEMORY_SCOPE_SYSTEM);
        if (__all(v != 0)) break;
      }
      asm volatile("" ::: "memory");  // no hoisting of staging loads above the poll
    }

    // plain pipelined b128 loads — addresses are fresh this step, no stale copies
    const short* st = staging + (size_t)t * 65536 + arow * 1024 + q * 8;
    s16x8 a[32];
#pragma unroll
    for (int cc = 0; cc < 32; ++cc) a[cc] = *(const s16x8*)(st + cc * 32);

    f32x4 cA0 = {0.f,0.f,0.f,0.f}, cA1 = {0.f,0.f,0.f,0.f};
    f32x4 cB0 = {0.f,0.f,0.f,0.f}, cB1 = {0.f,0.f,0.f,0.f};
#pragma unroll
    for (int cc = 0; cc < 32; ++cc) {
      if (cc & 1) {
        cB0 = mfma16(a[cc], bf[cc][0], cB0);
        cB1 = mfma16(a[cc], bf[cc][1], cB1);
      } else {
        cA0 = mfma16(a[cc], bf[cc][0], cA0);
        cA1 = mfma16(a[cc], bf[cc][1], cA1);
      }
    }
    f32x4 s0 = cA0 + cB0;
    f32x4 s1 = cA1 + cB1;

    // tanh + repack through LDS (512B, single wave)
    float h0v[4], h1v[4];
    if (q < 2) {
#pragma unroll
      for (int r = 0; r < 4; ++r) {
        h0v[r] = fast_tanh(s0[r] + xp0[r]);
        h1v[r] = fast_tanh(s1[r] + xp1[r]);
        lh[(lr + r) * 32 + m]      = f2bf(h0v[r]);
        lh[(lr + r) * 32 + 16 + m] = f2bf(h1v[r]);
      }
    }
    __syncthreads();

    // one 8B packed value per lane -> staging slot t+1 (write-through to L3)
    long long pk = ((const long long*)lh)[lane];
    {
      long long* sp = (long long*)(staging + (size_t)(t + 1) * 65536
                                   + (rowbase + prow) * 1024 + colbase + pcol);
      __hip_atomic_store(sp, pk, __ATOMIC_RELAXED, __HIP_MEMORY_SCOPE_SYSTEM);
    }
    __syncthreads();  // lh reads done before next step's writes

    asm volatile("s_waitcnt vmcnt(0)" ::: "memory");  // staging store acked at L3
    if (lane == 0)
      __hip_atomic_store(flags + t * 256 + g * 32 + c, 1,
                         __ATOMIC_RELAXED, __HIP_MEMORY_SCOPE_SYSTEM);

    // non-protocol fp32 h stores drain whenever (kernel-end flush covers later phases)
    if (q < 2) {
#pragma unroll
      for (int r = 0; r < 4; ++r) {
        int ro = (tb + gr + r) * 1024;
        hid[ro + colbase + m] = h0v[r];
        hid[ro + colbase + 16 + m] = h1v[r];
      }
    }
  }
}

// ---------------- host ----------------

extern "C" void kernel_launch(void* const* d_in, const int* in_sizes, int n_in,
                              void* d_out, int out_size, void* d_ws, size_t ws_size,
                              hipStream_t stream) {
  const float* x  = (const float*)d_in[0];
  const float* h0 = (const float*)d_in[1];
  const float* wI = (const float*)d_in[2];
  const float* wR = (const float*)d_in[3];
  const float* wO = (const float*)d_in[4];
  const float* bR = (const float*)d_in[5];
  const float* bO = (const float*)d_in[6];

  float* outputs = (float*)d_out;                    // [512*64][256]
  float* hid = outputs + 512 * 64 * 256;             // [512*64][1024]

  // workspace layout: ~85.6 MB total
  short* x_bf    = (short*)d_ws;                     // 8,388,608 bf16 (16 MB)
  short* wI_bf   = x_bf + 8388608;                   // 262,144 (0.5 MB)
  short* wO_bf   = wI_bf + 262144;                   // 262,144 (0.5 MB)
  short* staging = wO_bf + 262144;                   // 513*65536 bf16 (67.2 MB)
  int*   flags   = (int*)(staging + 513 * 65536);    // 512*8*32 ints (0.5 MB)

  hipMemsetAsync(flags, 0, 512 * 256 * sizeof(int), stream);
  cvt_bf16x4<<<8192, 256, 0, stream>>>(x, x_bf, 2097152);
  cvt_bf16x4<<<256, 256, 0, stream>>>(wI, wI_bf, 65536);
  cvt_bf16x4<<<256, 256, 0, stream>>>(wO, wO_bf, 65536);
  init_staging<<<256, 256, 0, stream>>>(h0, staging);

  // Phase A: xp = x*wI^T + bR  -> hidden region (in-place seed for recurrence)
  gemm_nt_bias<256><<<dim3(512, 16), 256, 0, stream>>>(x_bf, wI_bf, bR, hid, 1024);
  // Phase B: sequential recurrence (writes staging slots 1..512 = h_0..h_511)
  rnn_recur<<<256, 64, 0, stream>>>(wR, hid, staging, flags);
  // Phase C: outputs = h*wO^T + bO, reading bf16 h straight from the ring
  gemm_nt_bias<1024><<<dim3(512, 4), 256, 0, stream>>>(staging + 65536, wO_bf, bO, outputs, 256);
}